// Round 17
// baseline (987.989 us; speedup 1.0000x reference)
//
#include <hip/hip_runtime.h>

#define B_ 256
#define D_ 128
#define T_ 1024
#define H_ 64
#define G_ 192
#define TILE_T 64
#define NTILES 16
#define XGS 65    // ring t-stride: 65%32=1 -> 2-way max (free)
#define KC 16
#define WS 194    // w_s g-stride

typedef float f32x4 __attribute__((ext_vector_type(4)));

// Barrier-lockstep fused GRU. 1 launch, block = 1 batch row, 7 waves.
// ALL waves run the same 17x64-step loop with ONE s_barrier per step.
//   waves 0,1,2: scan (gate r/z/n). Pre-bar: xg read + dot + publish
//                (tagless f32 slot, parity dbuf). Post-bar: read 2 peer
//                slots (NO retry loop - barrier guarantees visibility),
//                replicated pointwise, h write.
//   waves 3..6 : producer slices on a static schedule per 64-step tile
//                (tile kp=tt>>6): ph0 issue 8 global b128 (vmcnt in
//                flight ACROSS barriers), ph6 LDS-write lat + zero acc,
//                ph 7+6c/8+6c/9..12+6c: W-chunk load/write/4x4 kk FMA,
//                ph55: ring-write burst (static reg indexing, rule #20).
// No atomics, no spin-polls anywhere: r8..r16 showed ~450cyc/step of
// invariant overhead robust to dot/hop implementation - the remaining
// common structure was poll retries (~130cyc LDS RT each, random
// overshoot) in scan hop + producer psync. s_barrier costs ~tens of cyc.
// Slot safety: writer(t+2,par) vs reader(t,par) separated by barrier(t+1).
__global__ __launch_bounds__(448) void gru_fused(
    const float* __restrict__ lat, const float* __restrict__ hidden_init,
    const float* __restrict__ W_ih, const float* __restrict__ W_hh,
    const float* __restrict__ b_ih, const float* __restrict__ b_hh,
    const float* __restrict__ head_w, const float* __restrict__ head_b,
    float* __restrict__ out)
{
    __shared__ float xg_s[2][G_ * XGS];   // 99,840 B ring [slot][g*XGS+t]
    __shared__ float lat_s[D_ * TILE_T];  // 32,768 B [d][t]
    __shared__ float w_s[KC * WS];        // 12,416 B [kk][g]
    __shared__ float h_priv[3][H_];       //    768 B per-scan-wave h copy
    __shared__ float slotv[2][3][H_];     //  1,536 B tagless dots [par][gate][lane]

    const int b    = blockIdx.x;
    const int tid  = threadIdx.x;
    const int lane = tid & 63;
    const int wid  = tid >> 6;

#define STEP_BARRIER() do {                                   \
        __builtin_amdgcn_sched_barrier(0);                    \
        asm volatile("s_waitcnt lgkmcnt(0)" ::: "memory");    \
        __builtin_amdgcn_s_barrier();                         \
        __builtin_amdgcn_sched_barrier(0);                    \
    } while (0)

    if (wid < 3) {
        // ============================ scan waves ============================
        __builtin_amdgcn_s_setprio(1);
        const int j   = lane;
        const int row = wid * H_ + j;     // r 0..63 | z 64..127 | n 128..191
        f32x4 w4[16];
        {
            const f32x4* W = (const f32x4*)(W_hh + (size_t)row * H_);
#pragma unroll
            for (int q = 0; q < 16; ++q) w4[q] = W[q];
        }
        asm volatile("" : "+v"(w4[0]), "+v"(w4[1]), "+v"(w4[2]), "+v"(w4[3]),
                          "+v"(w4[4]), "+v"(w4[5]), "+v"(w4[6]), "+v"(w4[7]),
                          "+v"(w4[8]), "+v"(w4[9]), "+v"(w4[10]), "+v"(w4[11]),
                          "+v"(w4[12]), "+v"(w4[13]), "+v"(w4[14]), "+v"(w4[15]));
        const float bias = b_hh[row];
        const float hw   = (wid == 0) ? head_w[j] : 0.f;
        const int o1 = (wid == 0) ? 1 : 0;
        const int o2 = (wid == 2) ? 1 : 2;
        float h = hidden_init[b * H_ + j];
        h_priv[wid][j] = h;               // own-wave write; first read at tt=64

        for (int tt = 0; tt < (NTILES + 1) * TILE_T; ++tt) {
            const int k  = (tt >> 6) - 1;         // consumer tile (-1: prologue)
            const int ph = tt & 63;
            const int par = tt & 1;
            float a = 0.f, xr = 0.f, xz = 0.f, xn = 0.f;
            if (k >= 0) {
                const int s = k & 1;
                xr = xg_s[s][(size_t)j * XGS + ph];
                xz = xg_s[s][(size_t)(H_ + j) * XGS + ph];
                xn = xg_s[s][(size_t)(2 * H_ + j) * XGS + ph];
                const f32x4* h4 = (const f32x4*)h_priv[wid];
                float a0 = 0.f, a1 = 0.f, a2 = 0.f, a3 = 0.f;
#pragma unroll
                for (int q = 0; q < 16; ++q) {
                    f32x4 hv = h4[q];             // broadcast read
                    a0 = fmaf(w4[q].x, hv.x, a0); a1 = fmaf(w4[q].y, hv.y, a1);
                    a2 = fmaf(w4[q].z, hv.z, a2); a3 = fmaf(w4[q].w, hv.w, a3);
                }
                a = ((a0 + a1) + (a2 + a3)) + bias;
                __hip_atomic_store(&slotv[par][wid][j], a, __ATOMIC_RELAXED,
                                   __HIP_MEMORY_SCOPE_WORKGROUP);
            }
            STEP_BARRIER();
            if (k >= 0) {
                float b1 = __hip_atomic_load(&slotv[par][o1][j], __ATOMIC_RELAXED,
                                             __HIP_MEMORY_SCOPE_WORKGROUP);
                float b2 = __hip_atomic_load(&slotv[par][o2][j], __ATOMIC_RELAXED,
                                             __HIP_MEMORY_SCOPE_WORKGROUP);
                float ar, az, an;
                if (wid == 0)      { ar = a;  az = b1; an = b2; }
                else if (wid == 1) { ar = b1; az = a;  an = b2; }
                else               { ar = b1; az = b2; an = a;  }
                float r   = __builtin_amdgcn_rcpf(1.f + __expf(-(xr + ar)));
                float z   = __builtin_amdgcn_rcpf(1.f + __expf(-(xz + az)));
                float pre = xn + r * an;
                float n   = fmaf(-2.f, __builtin_amdgcn_rcpf(__expf(2.f * pre) + 1.f), 1.f);
                h = fmaf(z, h - n, n);            // (1-z)n + zh
                h_priv[wid][j] = h;               // own-wave, in-order
            }
        }

        if (wid == 0) {
            out[B_ + b * H_ + j] = h;             // output 1: final hidden
            float v = h * hw;
#pragma unroll
            for (int off = 32; off > 0; off >>= 1) v += __shfl_down(v, off);
            if (lane == 0) out[b] = v + head_b[0];
        }
    } else {
        // =========================== producer waves ===========================
        const int p  = tid - 192;        // 0..255
        const int tx = p & 7;            // t-sub: t = tx*8 + jj
        const int gy = p >> 3;           // g-sub: g = gy*6 + i
        const float* latb = lat + (size_t)b * (D_ * T_);

        float bias[6];
#pragma unroll
        for (int i = 0; i < 6; ++i) bias[i] = b_ih[gy * 6 + i];

        f32x4 latv[8];                   // global-load staging (in flight over bar)
        float wreg[12];                  // W chunk staging
        float acc[8][6];
#pragma unroll
        for (int jj = 0; jj < 8; ++jj)
#pragma unroll
            for (int i = 0; i < 6; ++i) acc[jj][i] = 0.f;

        for (int tt = 0; tt < (NTILES + 1) * TILE_T; ++tt) {
            const int kp = tt >> 6;              // producer tile
            const int ph = tt & 63;
            if (kp <= NTILES - 1) {
                if (ph == 0) {
                    // issue 8 global b128 loads; vmcnt rides across barriers
#pragma unroll
                    for (int i = 0; i < 8; ++i) {
                        int f4 = p + 256 * i;
                        int d  = f4 >> 4;
                        int t4 = (f4 & 15) * 4;
                        latv[i] = *(const f32x4*)&latb[(size_t)d * T_ + kp * TILE_T + t4];
                    }
                } else if (ph == 6) {
                    // write lat tile to LDS; zero accumulators
#pragma unroll
                    for (int i = 0; i < 8; ++i) {
                        int f4 = p + 256 * i;
                        int d  = f4 >> 4;
                        int t4 = (f4 & 15) * 4;
                        *(f32x4*)&lat_s[d * 64 + t4] = latv[i];
                    }
#pragma unroll
                    for (int jj = 0; jj < 8; ++jj)
#pragma unroll
                        for (int i = 0; i < 6; ++i) acc[jj][i] = 0.f;
                } else if (ph >= 7 && ph <= 54) {
                    const int q = ph - 7;
                    const int c = q / 6;          // chunk 0..7
                    const int r = q - 6 * c;      // 0..5
                    if (r == 0) {
                        // issue W chunk loads (L2-hot after tile 0)
#pragma unroll
                        for (int i = 0; i < 12; ++i) {
                            int f = p + 256 * i;
                            int g = f >> 4, kkl = f & 15;
                            wreg[i] = W_ih[(size_t)g * D_ + c * KC + kkl];
                        }
                    } else if (r == 1) {
#pragma unroll
                        for (int i = 0; i < 12; ++i) {
                            int f = p + 256 * i;
                            int g = f >> 4, kkl = f & 15;
                            w_s[kkl * WS + g] = wreg[i];
                        }
                    } else {
                        // 4 kk of FMA
#pragma unroll
                        for (int u = 0; u < 4; ++u) {
                            const int kkl = (r - 2) * 4 + u;      // 0..15
                            const int kg  = c * KC + kkl;         // global k
                            f32x4 l0 = *(const f32x4*)&lat_s[kg * 64 + tx * 8];
                            f32x4 l1 = *(const f32x4*)&lat_s[kg * 64 + tx * 8 + 4];
                            float2 w0 = *(const float2*)&w_s[kkl * WS + gy * 6];
                            float2 w1 = *(const float2*)&w_s[kkl * WS + gy * 6 + 2];
                            float2 w2 = *(const float2*)&w_s[kkl * WS + gy * 6 + 4];
                            float lv[8] = {l0.x, l0.y, l0.z, l0.w, l1.x, l1.y, l1.z, l1.w};
                            float wv[6] = {w0.x, w0.y, w1.x, w1.y, w2.x, w2.y};
#pragma unroll
                            for (int jj = 0; jj < 8; ++jj)
#pragma unroll
                                for (int i = 0; i < 6; ++i)
                                    acc[jj][i] = fmaf(lv[jj], wv[i], acc[jj][i]);
                        }
                    }
                } else if (ph == 55) {
                    // ring-write burst (static indices; ~48 DS ops, off-path)
                    float* xs = xg_s[kp & 1];
#pragma unroll
                    for (int i = 0; i < 6; ++i)
#pragma unroll
                        for (int jj = 0; jj < 8; ++jj)
                            xs[(size_t)(gy * 6 + i) * XGS + tx * 8 + jj] =
                                acc[jj][i] + bias[i];
                }
            }
            STEP_BARRIER();
        }
    }
#undef STEP_BARRIER
}

extern "C" void kernel_launch(void* const* d_in, const int* in_sizes, int n_in,
                              void* d_out, int out_size, void* d_ws, size_t ws_size,
                              hipStream_t stream)
{
    const float* lat   = (const float*)d_in[0];
    const float* hid0  = (const float*)d_in[1];
    const float* W_ih  = (const float*)d_in[2];
    const float* W_hh  = (const float*)d_in[3];
    const float* b_ih  = (const float*)d_in[4];
    const float* b_hh  = (const float*)d_in[5];
    const float* headw = (const float*)d_in[6];
    const float* headb = (const float*)d_in[7];
    float* out = (float*)d_out;

    gru_fused<<<dim3(B_), dim3(448), 0, stream>>>(
        lat, hid0, W_ih, W_hh, b_ih, b_hh, headw, headb, out);
}

// Round 18
// 464.480 us; speedup vs baseline: 2.1271x; 2.1271x over previous
//
#include <hip/hip_runtime.h>

#define B_ 256
#define D_ 128
#define T_ 1024
#define H_ 64
#define G_ 192
#define TILE_T 64
#define NTILES (T_ / TILE_T)   // 16
#define XGS 65                 // ring t-stride: 65%32=1 -> 2-way max (free)
#define KC 32                  // producer k-chunk (r8 value)
#define WS 194                 // w_s g-stride

typedef float f32x4 __attribute__((ext_vector_type(4)));
typedef float f32x2 __attribute__((ext_vector_type(2)));
typedef unsigned long long u64;

// Fused GRU, 1 launch. Block = 1 batch row, 7 waves, 1 block/CU.
// EXACT r8 skeleton (best proven 454us: slot hop, KC=32, 4 producers)
// + the issue-reduction bundle ONLY (clean A/B vs r8 on contention):
//   - producers: v_pk_fma_f32 accumulate (f32x2 accs) -> VALU issue halved
//   - producers: lat staging via ds_write_b128 (32 -> 8 DS ops/thread)
//   - scan: pk dot (f32x4 a4) -> dot issue halved
// r15/r16 tested these CONFOUNDED with KC=16 (from r14's LDS overflow);
// r17's per-step s_barrier lockstep regressed 2x (arrival jitter) - reverted.
__global__ __launch_bounds__(448, 2) void gru_fused(
    const float* __restrict__ lat, const float* __restrict__ hidden_init,
    const float* __restrict__ W_ih, const float* __restrict__ W_hh,
    const float* __restrict__ b_ih, const float* __restrict__ b_hh,
    const float* __restrict__ head_w, const float* __restrict__ head_b,
    float* __restrict__ out)
{
    __shared__ float xg_s[2][G_ * XGS];     // 99,840 B ring [slot][g*XGS+t]
    __shared__ float lat_s[D_ * TILE_T];    // 32,768 B [d][t]
    __shared__ float w_s[KC * WS];          // 24,832 B [kk][g]
    __shared__ float h_priv[3][H_];         // per-scan-wave private h copy
    __shared__ u64  slot[3][2][H_];         // [gate][parity][lane] {tag|val}
    __shared__ unsigned prod_done[2], cons_done[2], pbar;

    const int b    = blockIdx.x;
    const int tid  = threadIdx.x;
    const int lane = tid & 63;
    const int wid  = tid >> 6;

    if (tid < 2) { prod_done[tid] = 0u; cons_done[tid] = 0u; }
    if (tid == 2) pbar = 0u;
    if (tid < 192) { slot[tid >> 6][0][tid & 63] = 0ull;
                     slot[tid >> 6][1][tid & 63] = 0ull; }
    __syncthreads();   // only workgroup barrier (all 7 waves present)

    if (wid < 3) {
        // =============== scan: one gate-dot per wave, 1 hop/step ===============
        __builtin_amdgcn_s_setprio(1);
        const int j   = lane;
        const int row = wid * H_ + j;        // rows: r 0..63 | z 64..127 | n 128..191
        f32x4 w4[16];
        {
            const f32x4* W = (const f32x4*)(W_hh + (size_t)row * H_);
#pragma unroll
            for (int q = 0; q < 16; ++q) w4[q] = W[q];
        }
        asm volatile("" : "+v"(w4[0]), "+v"(w4[1]), "+v"(w4[2]), "+v"(w4[3]),
                          "+v"(w4[4]), "+v"(w4[5]), "+v"(w4[6]), "+v"(w4[7]),
                          "+v"(w4[8]), "+v"(w4[9]), "+v"(w4[10]), "+v"(w4[11]),
                          "+v"(w4[12]), "+v"(w4[13]), "+v"(w4[14]), "+v"(w4[15]));
        const float bias = b_hh[row];
        const float hw   = (wid == 0) ? head_w[j] : 0.f;
        const int o1 = (wid == 0) ? 1 : 0;
        const int o2 = (wid == 2) ? 1 : 2;
        float h = hidden_init[b * H_ + j];
        unsigned sg = 0;

        for (int k = 0; k < NTILES; ++k) {
            const int s = k & 1;
            const unsigned tgt = 4u * (unsigned)((k >> 1) + 1);   // 4 producers
            while (__hip_atomic_load(&prod_done[s], __ATOMIC_ACQUIRE,
                                     __HIP_MEMORY_SCOPE_WORKGROUP) < tgt)
                __builtin_amdgcn_s_sleep(1);
            const float* xr_p = &xg_s[s][(size_t)j * XGS];
            const float* xz_p = &xg_s[s][(size_t)(H_ + j) * XGS];
            const float* xn_p = &xg_s[s][(size_t)(2 * H_ + j) * XGS];

#pragma unroll 2
            for (int t = 0; t < TILE_T; ++t, ++sg) {
                const int par = (int)(sg & 1u);
                h_priv[wid][j] = h;                  // within-wave DS order
                float xr = xr_p[t], xz = xz_p[t], xn = xn_p[t];
                const f32x4* h4 = (const f32x4*)h_priv[wid];
                f32x4 a4 = {0.f, 0.f, 0.f, 0.f};
#pragma unroll
                for (int q = 0; q < 16; ++q)
                    a4 += w4[q] * h4[q];             // v_pk_fma_f32 x2
                float a = ((a4.x + a4.y) + (a4.z + a4.w)) + bias;
                const unsigned want = sg + 1;

                // publish my dot, then poll the other two (single hop, r8 exact)
                u64 pk = ((u64)want << 32) | (u64)__builtin_bit_cast(unsigned, a);
                __hip_atomic_store(&slot[wid][par][j], pk, __ATOMIC_RELAXED,
                                   __HIP_MEMORY_SCOPE_WORKGROUP);
                u64 v1, v2;
                do {
                    v1 = __hip_atomic_load(&slot[o1][par][j], __ATOMIC_RELAXED,
                                           __HIP_MEMORY_SCOPE_WORKGROUP);
                    v2 = __hip_atomic_load(&slot[o2][par][j], __ATOMIC_RELAXED,
                                           __HIP_MEMORY_SCOPE_WORKGROUP);
                } while ((unsigned)(v1 >> 32) != want || (unsigned)(v2 >> 32) != want);
                float b1 = __builtin_bit_cast(float, (unsigned)v1);
                float b2 = __builtin_bit_cast(float, (unsigned)v2);

                float ar, az, an;
                if (wid == 0)      { ar = a;  az = b1; an = b2; }
                else if (wid == 1) { ar = b1; az = a;  an = b2; }
                else               { ar = b1; az = b2; an = a;  }

                // replicated pointwise (identical FP ops in all 3 waves)
                float r   = __builtin_amdgcn_rcpf(1.f + __expf(-(xr + ar)));
                float z   = __builtin_amdgcn_rcpf(1.f + __expf(-(xz + az)));
                float pre = xn + r * an;
                float n   = fmaf(-2.f, __builtin_amdgcn_rcpf(__expf(2.f * pre) + 1.f), 1.f);
                h = fmaf(z, h - n, n);               // (1-z)n + zh
            }
            if (lane == 0)   // each scan wave releases the tile (producers wait 3)
                __hip_atomic_fetch_add(&cons_done[s], 1u, __ATOMIC_RELEASE,
                                       __HIP_MEMORY_SCOPE_WORKGROUP);
        }

        if (wid == 0) {   // all waves hold identical final h
            out[B_ + b * H_ + j] = h;
            float v = h * hw;
#pragma unroll
            for (int off = 32; off > 0; off >>= 1) v += __shfl_down(v, off);
            if (lane == 0) out[b] = v + head_b[0];
        }
    } else {
        // ====== producers: register-tiled GEMM (r8 skeleton, pk accs) ======
        const int p  = tid - 192;        // 0..255
        const int tx = p & 7;            // t-sub: t = tx*8 + 2*jj + hh
        const int gy = p >> 3;           // g-sub: g = gy*6 + i
        const float* latb = lat + (size_t)b * (D_ * T_);
        unsigned phase = 0;

        auto psync = [&]() {
            if ((p & 63) == 0)
                __hip_atomic_fetch_add(&pbar, 1u, __ATOMIC_RELEASE,
                                       __HIP_MEMORY_SCOPE_WORKGROUP);
            ++phase;
            while (__hip_atomic_load(&pbar, __ATOMIC_ACQUIRE,
                                     __HIP_MEMORY_SCOPE_WORKGROUP) < 4u * phase) {}
        };

        float bias[6];
#pragma unroll
        for (int i = 0; i < 6; ++i) bias[i] = b_ih[gy * 6 + i];

        for (int k = 0; k < NTILES; ++k) {
            const int s = k & 1, m = k >> 1;
            if (m >= 1) {
                while (__hip_atomic_load(&cons_done[s], __ATOMIC_ACQUIRE,
                                         __HIP_MEMORY_SCOPE_WORKGROUP) < 3u * (unsigned)m)
                    __builtin_amdgcn_s_sleep(1);
            }
            psync();   // all producers past previous tile's lat_s/w_s

            // stage lat tile [d][t] via float4 both sides (8 DS ops/thread;
            // each 16-lane group writes one contiguous 256B row: conflict-free)
#pragma unroll
            for (int i = 0; i < 8; ++i) {
                int f4 = p + 256 * i;          // [0,2048)
                int d  = f4 >> 4;
                int t4 = (f4 & 15) * 4;
                *(f32x4*)&lat_s[d * 64 + t4] =
                    *(const f32x4*)&latb[(size_t)d * T_ + k * TILE_T + t4];
            }

            f32x2 acc2[4][6];                  // [t-pair][g] packed accs
#pragma unroll
            for (int jj = 0; jj < 4; ++jj)
#pragma unroll
                for (int i = 0; i < 6; ++i) acc2[jj][i] = f32x2{0.f, 0.f};

            for (int kc = 0; kc < D_; kc += KC) {
                psync();   // lat_s staged / previous w_s consumed
#pragma unroll
                for (int i = 0; i < (G_ * KC) / 256; ++i) {   // 24/thread
                    int f = p + 256 * i;
                    int g = f >> 5, kk = f & 31;
                    w_s[kk * WS + g] = W_ih[(size_t)g * D_ + kc + kk];
                }
                psync();   // w_s ready
#pragma unroll 4
                for (int kk = 0; kk < KC; ++kk) {
                    f32x4 l0 = *(const f32x4*)&lat_s[(kc + kk) * 64 + tx * 8];
                    f32x4 l1 = *(const f32x4*)&lat_s[(kc + kk) * 64 + tx * 8 + 4];
                    f32x2 lv2[4] = {f32x2{l0.x, l0.y}, f32x2{l0.z, l0.w},
                                    f32x2{l1.x, l1.y}, f32x2{l1.z, l1.w}};
                    float2 w0 = *(const float2*)&w_s[kk * WS + gy * 6];
                    float2 w1 = *(const float2*)&w_s[kk * WS + gy * 6 + 2];
                    float2 w2 = *(const float2*)&w_s[kk * WS + gy * 6 + 4];
                    float wv[6] = {w0.x, w0.y, w1.x, w1.y, w2.x, w2.y};
#pragma unroll
                    for (int jj = 0; jj < 4; ++jj)
#pragma unroll
                        for (int i = 0; i < 6; ++i)
                            acc2[jj][i] += lv2[jj] * f32x2{wv[i], wv[i]};  // v_pk_fma_f32
                }
            }

            // write tile to ring slot (r8 layout)
            float* xs = xg_s[s];
#pragma unroll
            for (int i = 0; i < 6; ++i)
#pragma unroll
                for (int jj = 0; jj < 4; ++jj) {
                    xs[(size_t)(gy * 6 + i) * XGS + tx * 8 + 2 * jj + 0] = acc2[jj][i].x + bias[i];
                    xs[(size_t)(gy * 6 + i) * XGS + tx * 8 + 2 * jj + 1] = acc2[jj][i].y + bias[i];
                }

            if ((p & 63) == 0)
                __hip_atomic_fetch_add(&prod_done[s], 1u, __ATOMIC_RELEASE,
                                       __HIP_MEMORY_SCOPE_WORKGROUP);
        }
    }
}

extern "C" void kernel_launch(void* const* d_in, const int* in_sizes, int n_in,
                              void* d_out, int out_size, void* d_ws, size_t ws_size,
                              hipStream_t stream)
{
    const float* lat   = (const float*)d_in[0];
    const float* hid0  = (const float*)d_in[1];
    const float* W_ih  = (const float*)d_in[2];
    const float* W_hh  = (const float*)d_in[3];
    const float* b_ih  = (const float*)d_in[4];
    const float* b_hh  = (const float*)d_in[5];
    const float* headw = (const float*)d_in[6];
    const float* headb = (const float*)d_in[7];
    float* out = (float*)d_out;

    gru_fused<<<dim3(B_), dim3(448), 0, stream>>>(
        lat, hid0, W_ih, W_hh, b_ih, b_hh, headw, headb, out);
}